// Round 2
// baseline (214.792 us; speedup 1.0000x reference)
//
#include <hip/hip_runtime.h>
#include <hip/hip_fp16.h>

#define Bn   8
#define CM_  64
#define CIN  128   // mem(64) + que(64)
#define CO_  64
#define Hn   128
#define Wn   128
#define Kn   9
#define COFF 27    // 18 offset + 9 mask channels
#define HW   (Hn * Wn)

typedef __attribute__((ext_vector_type(8))) _Float16 f16x8;  // 8 f16 = 4 VGPRs
typedef __attribute__((ext_vector_type(4))) float f32x4;

__device__ __forceinline__ unsigned h22u(__half2 h) {
    unsigned u; __builtin_memcpy(&u, &h, 4); return u;
}
__device__ __forceinline__ __half2 u2h2(unsigned u) {
    __half2 h; __builtin_memcpy(&h, &u, 4); return h;
}
__device__ __forceinline__ unsigned short f2h(float x) {
    __half h = __float2half(x);
    unsigned short u; __builtin_memcpy(&u, &h, 2); return u;
}

// ---------------------------------------------------------------------------
// Kernel T: transpose concat(mem,que) [b][c][px] fp32 -> xT[b][px][c] f16.
// ---------------------------------------------------------------------------
__global__ __launch_bounds__(256) void transpose_kernel(
    const float* __restrict__ mem, const float* __restrict__ que,
    uint4* __restrict__ xT4)
{
    __shared__ unsigned tile[64 * 65];

    const int bb   = blockIdx.x & 7;
    const int pix0 = (blockIdx.x >> 3) * 64;
    const int tid  = threadIdx.x;
    const int pxL  = tid & 63;
    const int cg   = tid >> 6;

    const float* mb = mem + (size_t)bb * CM_ * HW + pix0 + pxL;
    const float* qb = que + (size_t)bb * CM_ * HW + pix0 + pxL;

    #pragma unroll
    for (int i = 0; i < 16; ++i) {
        const int c = cg * 32 + 2 * i;
        const float v0 = (c < CM_) ? mb[(size_t)c * HW]       : qb[(size_t)(c - CM_) * HW];
        const float v1 = (c + 1 < CM_) ? mb[(size_t)(c + 1) * HW] : qb[(size_t)(c + 1 - CM_) * HW];
        tile[pxL * 65 + cg * 16 + i] = h22u(__floats2half2_rn(v0, v1));
    }
    __syncthreads();

    uint4* dst = xT4 + (size_t)(bb * HW + pix0) * 16;
    #pragma unroll
    for (int p = 0; p < 4; ++p) {
        const int G  = p * 256 + tid;
        const int px = G >> 4;
        const int u  = G & 15;
        uint4 v;
        v.x = tile[px * 65 + u * 4 + 0];
        v.y = tile[px * 65 + u * 4 + 1];
        v.z = tile[px * 65 + u * 4 + 2];
        v.w = tile[px * 65 + u * 4 + 3];
        dst[G] = v;
    }
}

// ---------------------------------------------------------------------------
// Kernel W: pack w_def AND w_off into MFMA A-fragment order (f16), one launch.
//   wpd: idx = (((g*9+k)*2+f)*64+L)*8+j  -> W[o=g*16+(L&15)][c=f*32+(L>>4)*8+j], tap k
//   wpo: idx = (((ot*9+tap)*4+s)*64+L)*8+j -> o=ot*16+(L&15) (pad 27->32), c=s*32+...
// ---------------------------------------------------------------------------
__global__ __launch_bounds__(256) void wprep_all_kernel(
    const float* __restrict__ w_def, const float* __restrict__ w_off,
    unsigned short* __restrict__ wpd, unsigned short* __restrict__ wpo)
{
    int idx = blockIdx.x * 256 + threadIdx.x;
    if (idx < CO_ * CM_ * Kn) {
        const int j  = idx & 7;
        const int L  = (idx >> 3) & 63;
        const int f  = (idx >> 9) & 1;
        const int gk = idx >> 10;
        const int k  = gk % 9;
        const int g  = gk / 9;
        const int o  = g * 16 + (L & 15);
        const int c  = f * 32 + (L >> 4) * 8 + j;
        wpd[idx] = f2h(w_def[(size_t)(o * CM_ + c) * Kn + k]);
        return;
    }
    idx -= CO_ * CM_ * Kn;
    if (idx < 2 * 9 * 4 * 64 * 8) {
        const int j   = idx & 7;
        const int L   = (idx >> 3) & 63;
        const int s   = (idx >> 9) & 3;
        const int r   = idx >> 11;
        const int tap = r % 9;
        const int ot  = r / 9;
        const int o   = ot * 16 + (L & 15);
        const int c   = s * 32 + (L >> 4) * 8 + j;
        wpo[idx] = (o < COFF) ? f2h(w_off[(size_t)(o * CIN + c) * Kn + tap])
                              : (unsigned short)0;
    }
}

// ---------------------------------------------------------------------------
// Fused kernel: offset-conv GEMM (phase 1, B-fragments loaded DIRECTLY from
// L2-resident xT4 -- no LDS window, no phase-1 barriers) + deformable
// sampling + deform GEMM (phase 2). Block = 64-px row strip, all 64 outs.
// LDS (24,576 B -> 6 blocks/CU by LDS):
//   offl[27][64] fp32 at offset 0; smp4[2][64][8] at offset 8192.
// Plain __launch_bounds__(256): let the allocator take its natural ~70-90
// VGPRs (round-1's (256,6) forced spills: VGPR 40, +43MB HBM writes).
// ---------------------------------------------------------------------------
__global__ __launch_bounds__(256) void fused_deform_kernel(
    const uint4* __restrict__ xT4, const uint4* __restrict__ wpo,
    const uint4* __restrict__ wpd, const float* __restrict__ b_off,
    float* __restrict__ out)
{
    __shared__ __align__(16) char lds[24576];
    float* offl = (float*)lds;                          // 27*64*4 = 6,912 B
    uint4* smp4 = (uint4*)(lds + 8192);                 // 2*64*8*16 = 16,384 B

    const int bb   = blockIdx.x & 7;                    // batch -> XCD affinity
    const int pix0 = (blockIdx.x >> 3) * 64;
    const int h0   = pix0 >> 7;
    const int w0   = pix0 & 127;
    const int tid  = threadIdx.x;
    const int wv   = tid >> 6;
    const int lane = tid & 63;
    const int quad = lane >> 4;
    const int lrow = lane & 15;

    const uint4* xb = xT4 + (size_t)bb * HW * 16;

    // ======== phase 1: offset-conv GEMM, B-fragments direct from L2 ========
    {
        const int ot   = wv >> 1;
        const int sub0 = (wv & 1) * 2;

        f32x4 oacc[2];
        #pragma unroll
        for (int t = 0; t < 2; ++t)
            #pragma unroll
            for (int r = 0; r < 4; ++r) {
                const int o = ot * 16 + quad * 4 + r;
                oacc[t][r] = (o < COFF) ? b_off[o] : 0.0f;
            }

        #pragma unroll
        for (int tap = 0; tap < 9; ++tap) {
            const int rr = tap / 3;
            const int cc = tap % 3;
            const int y  = h0 + rr - 1;
            if (y >= 0 && y < Hn) {          // wave-uniform row validity
                const uint4* ap = wpo + (size_t)((ot * 9 + tap) * 4) * 64 + lane;
                f16x8 a[4];
                #pragma unroll
                for (int s = 0; s < 4; ++s)
                    a[s] = __builtin_bit_cast(f16x8, ap[s * 64]);

                #pragma unroll
                for (int t = 0; t < 2; ++t) {
                    const int pl   = (sub0 + t) * 16 + lrow;
                    const int xcol = w0 + pl + cc - 1;
                    const bool ok  = (xcol >= 0) & (xcol < Wn);
                    const int xc   = min(max(xcol, 0), Wn - 1);
                    const uint4* bp = xb + (size_t)(y * Wn + xc) * 16;
                    #pragma unroll
                    for (int s = 0; s < 4; ++s) {
                        uint4 v = bp[s * 4 + quad];     // B-frag: one uint4 of xT4
                        if (!ok) v = make_uint4(0, 0, 0, 0);
                        oacc[t] = __builtin_amdgcn_mfma_f32_16x16x32_f16(
                            a[s], __builtin_bit_cast(f16x8, v), oacc[t], 0, 0, 0);
                    }
                }
            }
        }

        #pragma unroll
        for (int t = 0; t < 2; ++t) {
            const int pl = (sub0 + t) * 16 + lrow;
            #pragma unroll
            for (int r = 0; r < 4; ++r) {
                const int o = ot * 16 + quad * 4 + r;
                if (o < COFF) offl[o * 64 + pl] = oacc[t][r];
            }
        }
        __syncthreads();   // offl visible to all (no LDS aliasing in phase 1)
    }

    // ======== phase 2: deformable sampling + deform GEMM ========
    const int chunk = lane & 7;
    const int psub  = lane >> 3;

    const int pM = pix0 + lane;        // pixel-major identity (lane = pixel)
    const int hM = pM >> 7;
    const int wM = pM & 127;

    f32x4 acc[4];
    #pragma unroll
    for (int i = 0; i < 4; ++i) acc[i] = (f32x4){0.f, 0.f, 0.f, 0.f};

    __half2 W00h[2], W01h[2], W10h[2], W11h[2];
    uint4   G00[2], G01[2], G10[2], G11[2];

    auto prep = [&](int k) {
        const float dy = offl[(2 * k    ) * 64 + lane];
        const float dx = offl[(2 * k + 1) * 64 + lane];
        const float mk = offl[(18 + k   ) * 64 + lane];
        const float py = (float)(hM + k / 3 - 1) + dy;
        const float px = (float)(wM + k % 3 - 1) + dx;
        const float y0f = floorf(py), x0f = floorf(px);
        const float fy = py - y0f,  fx = px - x0f;
        const int y0 = (int)y0f, x0 = (int)x0f;
        const int y1 = y0 + 1,   x1 = x0 + 1;
        const bool vy0 = (y0 >= 0) & (y0 < Hn);
        const bool vy1 = (y1 >= 0) & (y1 < Hn);
        const bool vx0 = (x0 >= 0) & (x0 < Wn);
        const bool vx1 = (x1 >= 0) & (x1 < Wn);
        const float w00 = (1.f - fy) * (1.f - fx) * (float)(vy0 & vx0) * mk;
        const float w01 = (1.f - fy) * fx         * (float)(vy0 & vx1) * mk;
        const float w10 = fy * (1.f - fx)         * (float)(vy1 & vx0) * mk;
        const float w11 = fy * fx                 * (float)(vy1 & vx1) * mk;
        const int y0c = min(max(y0, 0), Hn - 1);
        const int y1c = min(max(y1, 0), Hn - 1);
        const int x0c = min(max(x0, 0), Wn - 1);
        const int x1c = min(max(x1, 0), Wn - 1);
        const int i00 = y0c * Wn + x0c, i01 = y0c * Wn + x1c;
        const int i10 = y1c * Wn + x0c, i11 = y1c * Wn + x1c;

        #pragma unroll
        for (int g = 0; g < 2; ++g) {
            const int pl = g * 32 + wv * 8 + psub;
            W00h[g] = __float2half2_rn(__shfl(w00, pl, 64));
            W01h[g] = __float2half2_rn(__shfl(w01, pl, 64));
            W10h[g] = __float2half2_rn(__shfl(w10, pl, 64));
            W11h[g] = __float2half2_rn(__shfl(w11, pl, 64));
        const int I00 = __shfl(i00, pl, 64);
        const int I01 = __shfl(i01, pl, 64);
        const int I10 = __shfl(i10, pl, 64);
        const int I11 = __shfl(i11, pl, 64);
            G00[g] = xb[(size_t)I00 * 16 + chunk];
            G01[g] = xb[(size_t)I01 * 16 + chunk];
            G10[g] = xb[(size_t)I10 * 16 + chunk];
            G11[g] = xb[(size_t)I11 * 16 + chunk];
        }
    };

    auto blendwrite = [&](int buf) {
        #pragma unroll
        for (int g = 0; g < 2; ++g) {
            const int pl = g * 32 + wv * 8 + psub;
            const unsigned u00[4] = {G00[g].x, G00[g].y, G00[g].z, G00[g].w};
            const unsigned u01[4] = {G01[g].x, G01[g].y, G01[g].z, G01[g].w};
            const unsigned u10[4] = {G10[g].x, G10[g].y, G10[g].z, G10[g].w};
            const unsigned u11[4] = {G11[g].x, G11[g].y, G11[g].z, G11[g].w};
            unsigned pk[4];
            #pragma unroll
            for (int d = 0; d < 4; ++d) {
                __half2 s = __hmul2(u2h2(u00[d]), W00h[g]);
                s = __hfma2(u2h2(u01[d]), W01h[g], s);
                s = __hfma2(u2h2(u10[d]), W10h[g], s);
                s = __hfma2(u2h2(u11[d]), W11h[g], s);
                pk[d] = h22u(s);
            }
            smp4[buf * 512 + pl * 8 + (chunk ^ (pl & 7))] =
                make_uint4(pk[0], pk[1], pk[2], pk[3]);
        }
    };

    prep(0);
    blendwrite(0);
    __syncthreads();

    #pragma unroll
    for (int k = 0; k < Kn; ++k) {
        const int cur = k & 1;

        if (k < Kn - 1) prep(k + 1);     // gathers in flight during MFMA

        const uint4* wpk = wpd + (size_t)((wv * 9 + k) * 2) * 64 + lane;
        const f16x8 a0 = __builtin_bit_cast(f16x8, wpk[0]);
        const f16x8 a1 = __builtin_bit_cast(f16x8, wpk[64]);

        #pragma unroll
        for (int nt = 0; nt < 4; ++nt) {
            const int pm = nt * 16 + lrow;
            const f16x8 b0 = __builtin_bit_cast(f16x8,
                smp4[cur * 512 + pm * 8 + ( quad      ^ (pm & 7))]);
            const f16x8 b1 = __builtin_bit_cast(f16x8,
                smp4[cur * 512 + pm * 8 + ((quad + 4) ^ (pm & 7))]);
            acc[nt] = __builtin_amdgcn_mfma_f32_16x16x32_f16(a0, b0, acc[nt], 0, 0, 0);
            acc[nt] = __builtin_amdgcn_mfma_f32_16x16x32_f16(a1, b1, acc[nt], 0, 0, 0);
        }

        if (k < Kn - 1) blendwrite(cur ^ 1);
        __syncthreads();
    }

    const int obase = (wv << 4) + (quad << 2);
    #pragma unroll
    for (int nt = 0; nt < 4; ++nt) {
        const int pp = pix0 + nt * 16 + lrow;
        #pragma unroll
        for (int r = 0; r < 4; ++r)
            out[(size_t)(bb * CO_ + obase + r) * HW + pp] = acc[nt][r];
    }
}

extern "C" void kernel_launch(void* const* d_in, const int* in_sizes, int n_in,
                              void* d_out, int out_size, void* d_ws, size_t ws_size,
                              hipStream_t stream) {
    const float* mem   = (const float*)d_in[0];
    const float* que   = (const float*)d_in[1];
    const float* w_off = (const float*)d_in[2];
    const float* b_off = (const float*)d_in[3];
    const float* w_def = (const float*)d_in[4];
    float* out = (float*)d_out;

    char* ws = (char*)d_ws;
    unsigned short* wpd = (unsigned short*)ws;             //  73,728 B
    unsigned short* wpo = (unsigned short*)(ws + 73728);   //  73,728 B
    uint4*          xT4 = (uint4*)(ws + 147456);           //  33,554,432 B

    transpose_kernel<<<2048, 256, 0, stream>>>(mem, que, xT4);
    wprep_all_kernel<<<288, 256, 0, stream>>>(w_def, w_off, wpd, wpo);
    fused_deform_kernel<<<2048, 256, 0, stream>>>(
        xT4, (const uint4*)wpo, (const uint4*)wpd, b_off, out);
}

// Round 3
// 210.743 us; speedup vs baseline: 1.0192x; 1.0192x over previous
//
#include <hip/hip_runtime.h>
#include <hip/hip_fp16.h>

#define Bn   8
#define CM_  64
#define CIN  128   // mem(64) + que(64)
#define CO_  64
#define Hn   128
#define Wn   128
#define Kn   9
#define COFF 27    // 18 offset + 9 mask channels
#define HW   (Hn * Wn)

typedef __attribute__((ext_vector_type(8))) _Float16 f16x8;  // 8 f16 = 4 VGPRs
typedef __attribute__((ext_vector_type(4))) float f32x4;

__device__ __forceinline__ unsigned h22u(__half2 h) {
    unsigned u; __builtin_memcpy(&u, &h, 4); return u;
}
__device__ __forceinline__ __half2 u2h2(unsigned u) {
    __half2 h; __builtin_memcpy(&h, &u, 4); return h;
}
__device__ __forceinline__ unsigned short f2h(float x) {
    __half h = __float2half(x);
    unsigned short u; __builtin_memcpy(&u, &h, 2); return u;
}

// ---------------------------------------------------------------------------
// Kernel T: transpose concat(mem,que) [b][c][px] fp32 -> xT[b][px][c] f16.
// ---------------------------------------------------------------------------
__global__ __launch_bounds__(256) void transpose_kernel(
    const float* __restrict__ mem, const float* __restrict__ que,
    uint4* __restrict__ xT4)
{
    __shared__ unsigned tile[64 * 65];

    const int bb   = blockIdx.x & 7;
    const int pix0 = (blockIdx.x >> 3) * 64;
    const int tid  = threadIdx.x;
    const int pxL  = tid & 63;
    const int cg   = tid >> 6;

    const float* mb = mem + (size_t)bb * CM_ * HW + pix0 + pxL;
    const float* qb = que + (size_t)bb * CM_ * HW + pix0 + pxL;

    #pragma unroll
    for (int i = 0; i < 16; ++i) {
        const int c = cg * 32 + 2 * i;
        const float v0 = (c < CM_) ? mb[(size_t)c * HW]       : qb[(size_t)(c - CM_) * HW];
        const float v1 = (c + 1 < CM_) ? mb[(size_t)(c + 1) * HW] : qb[(size_t)(c + 1 - CM_) * HW];
        tile[pxL * 65 + cg * 16 + i] = h22u(__floats2half2_rn(v0, v1));
    }
    __syncthreads();

    uint4* dst = xT4 + (size_t)(bb * HW + pix0) * 16;
    #pragma unroll
    for (int p = 0; p < 4; ++p) {
        const int G  = p * 256 + tid;
        const int px = G >> 4;
        const int u  = G & 15;
        uint4 v;
        v.x = tile[px * 65 + u * 4 + 0];
        v.y = tile[px * 65 + u * 4 + 1];
        v.z = tile[px * 65 + u * 4 + 2];
        v.w = tile[px * 65 + u * 4 + 3];
        dst[G] = v;
    }
}

// ---------------------------------------------------------------------------
// Kernel W: pack w_def AND w_off into MFMA A-fragment order (f16), one launch.
//   wpd (TAP-MAJOR now, so each tap's 8KB A-slice is contiguous / L1-friendly):
//     idx = (((k*4+g)*2+f)*64+L)*8+j -> W[o=g*16+(L&15)][c=f*32+(L>>4)*8+j], tap k
//   wpo: idx = (((ot*9+tap)*4+s)*64+L)*8+j -> o=ot*16+(L&15) (pad 27->32), c=s*32+...
// ---------------------------------------------------------------------------
__global__ __launch_bounds__(256) void wprep_all_kernel(
    const float* __restrict__ w_def, const float* __restrict__ w_off,
    unsigned short* __restrict__ wpd, unsigned short* __restrict__ wpo)
{
    int idx = blockIdx.x * 256 + threadIdx.x;
    if (idx < CO_ * CM_ * Kn) {
        const int j  = idx & 7;
        const int L  = (idx >> 3) & 63;
        const int f  = (idx >> 9) & 1;
        const int q  = idx >> 10;       // k*4 + g
        const int k  = q >> 2;
        const int g  = q & 3;
        const int o  = g * 16 + (L & 15);
        const int c  = f * 32 + (L >> 4) * 8 + j;
        wpd[idx] = f2h(w_def[(size_t)(o * CM_ + c) * Kn + k]);
        return;
    }
    idx -= CO_ * CM_ * Kn;
    if (idx < 2 * 9 * 4 * 64 * 8) {
        const int j   = idx & 7;
        const int L   = (idx >> 3) & 63;
        const int s   = (idx >> 9) & 3;
        const int r   = idx >> 11;
        const int tap = r % 9;
        const int ot  = r / 9;
        const int o   = ot * 16 + (L & 15);
        const int c   = s * 32 + (L >> 4) * 8 + j;
        wpo[idx] = (o < COFF) ? f2h(w_off[(size_t)(o * CIN + c) * Kn + tap])
                              : (unsigned short)0;
    }
}

// ---------------------------------------------------------------------------
// Fused kernel.
// Phase 1: offset-conv GEMM with channel-split LDS window (2 x 64-ch halves,
//          xw = 198 slots x 8 chunks = 25,344 B). 4 barriers total.
// Phase 2: BARRIER-FREE. Each wave owns 16 pixels x all 64 outputs:
//          offsets are lane-local (4 lanes/pixel redundant), sampling blend
//          writes a wave-PRIVATE smp tile (intra-wave lgkmcnt ordering only),
//          so waves drift across taps and hide each other's gather latency.
// LDS map (32,256 B -> 5 blocks/CU by LDS):
//   [0, 25,344)  : phase-1 xw  (dead in phase 2)
//   [0, 16,384)  : phase-2 smp (4 waves x 2 bufs x 16 px x 8 chunks, uint4)
//   [25,344, 32,256) : offl[27][64] fp32 (written end of phase 1, read phase 2)
// ---------------------------------------------------------------------------
__global__ __launch_bounds__(256) void fused_deform_kernel(
    const uint4* __restrict__ xT4, const uint4* __restrict__ wpo,
    const uint4* __restrict__ wpd, const float* __restrict__ b_off,
    float* __restrict__ out)
{
    __shared__ __align__(16) char lds[32256];
    uint4* xw   = (uint4*)lds;                          // phase 1 window
    float* offl = (float*)(lds + 25344);                // 27*64*4 = 6,912 B

    const int bb   = blockIdx.x & 7;                    // batch -> XCD affinity
    const int pix0 = (blockIdx.x >> 3) * 64;
    const int h0   = pix0 >> 7;
    const int w0   = pix0 & 127;
    const int tid  = threadIdx.x;
    const int wv   = tid >> 6;
    const int lane = tid & 63;
    const int quad = lane >> 4;
    const int lrow = lane & 15;

    const uint4* xb = xT4 + (size_t)bb * HW * 16;

    // ======== phase 1: offset-conv GEMM, two 64-channel halves ========
    {
        const int ot   = wv >> 1;
        const int sub0 = (wv & 1) * 2;

        f32x4 oacc[2];
        #pragma unroll
        for (int t = 0; t < 2; ++t)
            #pragma unroll
            for (int r = 0; r < 4; ++r) {
                const int o = ot * 16 + quad * 4 + r;
                oacc[t][r] = (o < COFF) ? b_off[o] : 0.0f;
            }

        #pragma unroll
        for (int Hh = 0; Hh < 2; ++Hh) {
            // ---- stage 3x66 window, 64-channel half Hh ----
            #pragma unroll
            for (int g = 0; g < 7; ++g) {
                const int idx = g * 256 + tid;
                if (idx < 198 * 8) {
                    const int slot = idx >> 3;
                    const int j    = idx & 7;
                    const int r    = slot / 66;
                    const int c    = slot - r * 66;
                    const int y    = h0 + r - 1;
                    const int x    = w0 + c - 1;
                    const bool ok  = (y >= 0) & (y < Hn) & (x >= 0) & (x < Wn);
                    uint4 v = make_uint4(0, 0, 0, 0);
                    if (ok) v = xb[(size_t)(y * Wn + x) * 16 + Hh * 8 + j];
                    xw[slot * 8 + (j ^ (slot & 7))] = v;
                }
            }
            __syncthreads();

            #pragma unroll
            for (int tap = 0; tap < 9; ++tap) {
                const int rr = tap / 3;
                const int cc = tap % 3;

                const uint4* ap = wpo
                    + (size_t)((ot * 9 + tap) * 4 + Hh * 2) * 64 + lane;
                f16x8 a[2];
                #pragma unroll
                for (int s = 0; s < 2; ++s)
                    a[s] = __builtin_bit_cast(f16x8, ap[s * 64]);

                #pragma unroll
                for (int t = 0; t < 2; ++t) {
                    const int pl   = (sub0 + t) * 16 + lrow;
                    const int slot = rr * 66 + pl + cc;
                    const int base = slot * 8;
                    const int sw   = slot & 7;
                    #pragma unroll
                    for (int s = 0; s < 2; ++s) {
                        const f16x8 bfrag = __builtin_bit_cast(f16x8,
                            xw[base + ((s * 4 + quad) ^ sw)]);
                        oacc[t] = __builtin_amdgcn_mfma_f32_16x16x32_f16(
                            a[s], bfrag, oacc[t], 0, 0, 0);
                    }
                }
            }
            if (Hh == 0) __syncthreads();   // xw reads done before restage
        }

        // offl region is disjoint from xw: write needs no pre-barrier
        #pragma unroll
        for (int t = 0; t < 2; ++t) {
            const int pl = (sub0 + t) * 16 + lrow;
            #pragma unroll
            for (int r = 0; r < 4; ++r) {
                const int o = ot * 16 + quad * 4 + r;
                if (o < COFF) offl[o * 64 + pl] = oacc[t][r];
            }
        }
        __syncthreads();   // offl visible; xw dead -> smp may overwrite
    }

    // ======== phase 2: wave-private tiles, BARRIER-FREE ========
    const int px = lane & 15;          // wave-local pixel 0..15
    const int cs = lane >> 4;          // chunk-set: this lane blends chunks cs, cs+4
    const int sp = wv * 16 + px;       // pixel within 64-strip
    const int pM = pix0 + sp;
    const int hM = pM >> 7;
    const int wM = pM & 127;

    uint4* smpW = (uint4*)lds + wv * 256;   // 2 bufs x 16 px x 8 chunks (4 KB/wave)

    f32x4 acc[4];
    #pragma unroll
    for (int i = 0; i < 4; ++i) acc[i] = (f32x4){0.f, 0.f, 0.f, 0.f};

    __half2 Wc00, Wc01, Wc10, Wc11;
    uint4 G[8];     // 4 corners x 2 chunk-halves (all accesses compile-time)

    auto prep = [&](int k) {
        const float dy = offl[(2 * k    ) * 64 + sp];
        const float dx = offl[(2 * k + 1) * 64 + sp];
        const float mk = offl[(18 + k   ) * 64 + sp];
        const float py  = (float)(hM + k / 3 - 1) + dy;
        const float pxf = (float)(wM + k % 3 - 1) + dx;
        const float y0f = floorf(py), x0f = floorf(pxf);
        const float fy = py - y0f,  fx = pxf - x0f;
        const int y0 = (int)y0f, x0 = (int)x0f;
        const int y1 = y0 + 1,   x1 = x0 + 1;
        const bool vy0 = (y0 >= 0) & (y0 < Hn);
        const bool vy1 = (y1 >= 0) & (y1 < Hn);
        const bool vx0 = (x0 >= 0) & (x0 < Wn);
        const bool vx1 = (x1 >= 0) & (x1 < Wn);
        const float w00 = (1.f - fy) * (1.f - fx) * (float)(vy0 & vx0) * mk;
        const float w01 = (1.f - fy) * fx         * (float)(vy0 & vx1) * mk;
        const float w10 = fy * (1.f - fx)         * (float)(vy1 & vx0) * mk;
        const float w11 = fy * fx                 * (float)(vy1 & vx1) * mk;
        Wc00 = __float2half2_rn(w00);
        Wc01 = __float2half2_rn(w01);
        Wc10 = __float2half2_rn(w10);
        Wc11 = __float2half2_rn(w11);
        const int y0c = min(max(y0, 0), Hn - 1);
        const int y1c = min(max(y1, 0), Hn - 1);
        const int x0c = min(max(x0, 0), Wn - 1);
        const int x1c = min(max(x1, 0), Wn - 1);
        const int i00 = y0c * Wn + x0c, i01 = y0c * Wn + x1c;
        const int i10 = y1c * Wn + x0c, i11 = y1c * Wn + x1c;
        const uint4* p00 = xb + (size_t)i00 * 16 + cs;
        const uint4* p01 = xb + (size_t)i01 * 16 + cs;
        const uint4* p10 = xb + (size_t)i10 * 16 + cs;
        const uint4* p11 = xb + (size_t)i11 * 16 + cs;
        G[0] = p00[0]; G[1] = p00[4];
        G[2] = p01[0]; G[3] = p01[4];
        G[4] = p10[0]; G[5] = p10[4];
        G[6] = p11[0]; G[7] = p11[4];
    };

    auto blend_store = [&](int buf) {
        #pragma unroll
        for (int hh = 0; hh < 2; ++hh) {
            const uint4 g00 = G[0 + hh], g01 = G[2 + hh];
            const uint4 g10 = G[4 + hh], g11 = G[6 + hh];
            const unsigned u00[4] = {g00.x, g00.y, g00.z, g00.w};
            const unsigned u01[4] = {g01.x, g01.y, g01.z, g01.w};
            const unsigned u10[4] = {g10.x, g10.y, g10.z, g10.w};
            const unsigned u11[4] = {g11.x, g11.y, g11.z, g11.w};
            unsigned pk[4];
            #pragma unroll
            for (int d = 0; d < 4; ++d) {
                __half2 s = __hmul2(u2h2(u00[d]), Wc00);
                s = __hfma2(u2h2(u01[d]), Wc01, s);
                s = __hfma2(u2h2(u10[d]), Wc10, s);
                s = __hfma2(u2h2(u11[d]), Wc11, s);
                pk[d] = h22u(s);
            }
            smpW[buf * 128 + px * 8 + ((cs + hh * 4) ^ (px & 7))] =
                make_uint4(pk[0], pk[1], pk[2], pk[3]);
        }
    };

    prep(0);
    #pragma unroll
    for (int k = 0; k < Kn; ++k) {
        const int buf = k & 1;
        blend_store(buf);                 // waits on this tap's gathers
        if (k < Kn - 1) prep(k + 1);      // next tap's gathers fly during MFMA

        const f16x8 b0 = __builtin_bit_cast(f16x8,
            smpW[buf * 128 + px * 8 + ( cs      ^ (px & 7))]);
        const f16x8 b1 = __builtin_bit_cast(f16x8,
            smpW[buf * 128 + px * 8 + ((cs + 4) ^ (px & 7))]);

        #pragma unroll
        for (int g = 0; g < 4; ++g) {
            const uint4* wpk = wpd + (size_t)((k * 4 + g) * 2) * 64 + lane;
            const f16x8 a0 = __builtin_bit_cast(f16x8, wpk[0]);
            const f16x8 a1 = __builtin_bit_cast(f16x8, wpk[64]);
            acc[g] = __builtin_amdgcn_mfma_f32_16x16x32_f16(a0, b0, acc[g], 0, 0, 0);
            acc[g] = __builtin_amdgcn_mfma_f32_16x16x32_f16(a1, b1, acc[g], 0, 0, 0);
        }
    }

    #pragma unroll
    for (int g = 0; g < 4; ++g) {
        #pragma unroll
        for (int r = 0; r < 4; ++r)
            out[(size_t)(bb * CO_ + g * 16 + cs * 4 + r) * HW + pM] = acc[g][r];
    }
}

extern "C" void kernel_launch(void* const* d_in, const int* in_sizes, int n_in,
                              void* d_out, int out_size, void* d_ws, size_t ws_size,
                              hipStream_t stream) {
    const float* mem   = (const float*)d_in[0];
    const float* que   = (const float*)d_in[1];
    const float* w_off = (const float*)d_in[2];
    const float* b_off = (const float*)d_in[3];
    const float* w_def = (const float*)d_in[4];
    float* out = (float*)d_out;

    char* ws = (char*)d_ws;
    unsigned short* wpd = (unsigned short*)ws;             //  73,728 B
    unsigned short* wpo = (unsigned short*)(ws + 73728);   //  73,728 B
    uint4*          xT4 = (uint4*)(ws + 147456);           //  33,554,432 B

    transpose_kernel<<<2048, 256, 0, stream>>>(mem, que, xT4);
    wprep_all_kernel<<<288, 256, 0, stream>>>(w_def, w_off, wpd, wpo);
    fused_deform_kernel<<<2048, 256, 0, stream>>>(
        xT4, (const uint4*)wpo, (const uint4*)wpd, b_off, out);
}

// Round 5
// 165.973 us; speedup vs baseline: 1.2941x; 1.2697x over previous
//
#include <hip/hip_runtime.h>
#include <hip/hip_fp16.h>

#define Bn   8
#define CM_  64
#define CIN  128   // mem(64) + que(64)
#define CO_  64
#define Hn   128
#define Wn   128
#define Kn   9
#define COFF 27    // 18 offset + 9 mask channels
#define HW   (Hn * Wn)

typedef __attribute__((ext_vector_type(8))) _Float16 f16x8;  // 8 f16 = 4 VGPRs
typedef __attribute__((ext_vector_type(4))) float f32x4;

__device__ __forceinline__ unsigned h22u(__half2 h) {
    unsigned u; __builtin_memcpy(&u, &h, 4); return u;
}
__device__ __forceinline__ __half2 u2h2(unsigned u) {
    __half2 h; __builtin_memcpy(&h, &u, 4); return h;
}
__device__ __forceinline__ unsigned short f2h(float x) {
    __half h = __float2half(x);
    unsigned short u; __builtin_memcpy(&u, &h, 2); return u;
}

// ---------------------------------------------------------------------------
// Kernel T: transpose concat(mem,que) [b][c][px] fp32 -> xT[b][px][c] f16.
// ---------------------------------------------------------------------------
__global__ __launch_bounds__(256) void transpose_kernel(
    const float* __restrict__ mem, const float* __restrict__ que,
    uint4* __restrict__ xT4)
{
    __shared__ unsigned tile[64 * 65];

    const int bb   = blockIdx.x & 7;
    const int pix0 = (blockIdx.x >> 3) * 64;
    const int tid  = threadIdx.x;
    const int pxL  = tid & 63;
    const int cg   = tid >> 6;

    const float* mb = mem + (size_t)bb * CM_ * HW + pix0 + pxL;
    const float* qb = que + (size_t)bb * CM_ * HW + pix0 + pxL;

    #pragma unroll
    for (int i = 0; i < 16; ++i) {
        const int c = cg * 32 + 2 * i;
        const float v0 = (c < CM_) ? mb[(size_t)c * HW]       : qb[(size_t)(c - CM_) * HW];
        const float v1 = (c + 1 < CM_) ? mb[(size_t)(c + 1) * HW] : qb[(size_t)(c + 1 - CM_) * HW];
        tile[pxL * 65 + cg * 16 + i] = h22u(__floats2half2_rn(v0, v1));
    }
    __syncthreads();

    uint4* dst = xT4 + (size_t)(bb * HW + pix0) * 16;
    #pragma unroll
    for (int p = 0; p < 4; ++p) {
        const int G  = p * 256 + tid;
        const int px = G >> 4;
        const int u  = G & 15;
        uint4 v;
        v.x = tile[px * 65 + u * 4 + 0];
        v.y = tile[px * 65 + u * 4 + 1];
        v.z = tile[px * 65 + u * 4 + 2];
        v.w = tile[px * 65 + u * 4 + 3];
        dst[G] = v;
    }
}

// ---------------------------------------------------------------------------
// Kernel W: pack w_def AND w_off into MFMA A-fragment order (f16), one launch.
//   wpd: idx = (((g*9+k)*2+f)*64+L)*8+j  -> W[o=g*16+(L&15)][c=f*32+(L>>4)*8+j], tap k
//   wpo: idx = (((ot*9+tap)*4+s)*64+L)*8+j -> o=ot*16+(L&15) (pad 27->32), c=s*32+...
// ---------------------------------------------------------------------------
__global__ __launch_bounds__(256) void wprep_all_kernel(
    const float* __restrict__ w_def, const float* __restrict__ w_off,
    unsigned short* __restrict__ wpd, unsigned short* __restrict__ wpo)
{
    int idx = blockIdx.x * 256 + threadIdx.x;
    if (idx < CO_ * CM_ * Kn) {
        const int j  = idx & 7;
        const int L  = (idx >> 3) & 63;
        const int f  = (idx >> 9) & 1;
        const int gk = idx >> 10;
        const int k  = gk % 9;
        const int g  = gk / 9;
        const int o  = g * 16 + (L & 15);
        const int c  = f * 32 + (L >> 4) * 8 + j;
        wpd[idx] = f2h(w_def[(size_t)(o * CM_ + c) * Kn + k]);
        return;
    }
    idx -= CO_ * CM_ * Kn;
    if (idx < 2 * 9 * 4 * 64 * 8) {
        const int j   = idx & 7;
        const int L   = (idx >> 3) & 63;
        const int s   = (idx >> 9) & 3;
        const int r   = idx >> 11;
        const int tap = r % 9;
        const int ot  = r / 9;
        const int o   = ot * 16 + (L & 15);
        const int c   = s * 32 + (L >> 4) * 8 + j;
        wpo[idx] = (o < COFF) ? f2h(w_off[(size_t)(o * CIN + c) * Kn + tap])
                              : (unsigned short)0;
    }
}

// ---------------------------------------------------------------------------
// Fused kernel: round-0 structure (monolithic phase-1 window, wave-owns-
// outputs phase 2) + DEPTH-2 gather pipeline in phase 2:
//   - GB[2][8]/WB[2] double-buffered: gathers for tap t issued at iter t-2,
//     consumed (blend+store) at iter t-1, MFMA'd at iter t -> a full
//     iteration (incl. barrier) of latency hiding instead of ~300 cyc.
//   - AF[2]: the 2 A-frags for tap t prefetched at iter t-1, so no vmcnt
//     drain in front of the MFMA cluster.
//   - bilinear weights/indices computed directly per gather-pixel (broadcast
//     offl reads), removing the 16x shfl chain per tap.
// LDS union (50,688 B -> 3 blocks/CU):
//   phase 1 : xw[198 slots][16 chunks] window (3 rows x 66 cols, f16x8 chunks)
//   phase 2 : offl[27][64] fp32 at offset 0; smp4[2][64][8] at offset 8192.
// ---------------------------------------------------------------------------
__global__ __launch_bounds__(256) void fused_deform_kernel(
    const uint4* __restrict__ xT4, const uint4* __restrict__ wpo,
    const uint4* __restrict__ wpd, const float* __restrict__ b_off,
    float* __restrict__ out)
{
    __shared__ __align__(16) char lds[198 * 16 * 16];   // 50,688 B
    uint4* xw   = (uint4*)lds;
    float* offl = (float*)lds;                          // 27*64*4 = 6,912 B
    uint4* smp4 = (uint4*)(lds + 8192);                 // 2*64*8*16 = 16,384 B

    const int bb   = blockIdx.x & 7;                    // batch -> XCD affinity
    const int pix0 = (blockIdx.x >> 3) * 64;
    const int h0   = pix0 >> 7;
    const int w0   = pix0 & 127;
    const int tid  = threadIdx.x;
    const int wv   = tid >> 6;
    const int lane = tid & 63;
    const int quad = lane >> 4;
    const int lrow = lane & 15;

    const uint4* xb = xT4 + (size_t)bb * HW * 16;

    // ======== phase 1: stage 3x66 window ========
    #pragma unroll
    for (int g = 0; g < 13; ++g) {
        const int idx = g * 256 + tid;
        if (idx < 198 * 16) {
            const int slot = idx >> 4;
            const int j    = idx & 15;
            const int r    = slot / 66;
            const int c    = slot - r * 66;
            const int y    = h0 + r - 1;
            const int x    = w0 + c - 1;
            const bool ok  = (y >= 0) & (y < Hn) & (x >= 0) & (x < Wn);
            uint4 v = make_uint4(0, 0, 0, 0);
            if (ok) v = xb[(size_t)(y * Wn + x) * 16 + j];
            xw[slot * 16 + (j ^ (slot & 7))] = v;
        }
    }
    __syncthreads();

    // ======== phase 1: offset-conv GEMM ========
    {
        const int ot   = wv >> 1;
        const int sub0 = (wv & 1) * 2;

        f32x4 oacc[2];
        #pragma unroll
        for (int t = 0; t < 2; ++t)
            #pragma unroll
            for (int r = 0; r < 4; ++r) {
                const int o = ot * 16 + quad * 4 + r;
                oacc[t][r] = (o < COFF) ? b_off[o] : 0.0f;
            }

        #pragma unroll
        for (int tap = 0; tap < 9; ++tap) {
            const int rr = tap / 3;
            const int cc = tap % 3;

            const uint4* ap = wpo + (size_t)((ot * 9 + tap) * 4) * 64 + lane;
            f16x8 a[4];
            #pragma unroll
            for (int s = 0; s < 4; ++s)
                a[s] = __builtin_bit_cast(f16x8, ap[s * 64]);

            #pragma unroll
            for (int t = 0; t < 2; ++t) {
                const int pl   = (sub0 + t) * 16 + lrow;
                const int slot = rr * 66 + pl + cc;
                const int base = slot * 16;
                const int sw   = slot & 7;
                #pragma unroll
                for (int s = 0; s < 4; ++s) {
                    const f16x8 bfrag = __builtin_bit_cast(f16x8,
                        xw[base + ((s * 4 + quad) ^ sw)]);
                    oacc[t] = __builtin_amdgcn_mfma_f32_16x16x32_f16(
                        a[s], bfrag, oacc[t], 0, 0, 0);
                }
            }
        }
        __syncthreads();   // all xw reads complete before offl overwrite

        #pragma unroll
        for (int t = 0; t < 2; ++t) {
            const int pl = (sub0 + t) * 16 + lrow;
            #pragma unroll
            for (int r = 0; r < 4; ++r) {
                const int o = ot * 16 + quad * 4 + r;
                if (o < COFF) offl[o * 64 + pl] = oacc[t][r];
            }
        }
        __syncthreads();   // offl visible to all
    }

    // ======== phase 2: deformable sampling + deform GEMM, depth-2 ========
    const int chunk = lane & 7;
    const int psub  = lane >> 3;

    // this lane's two gather pixels (g = 0,1), fixed for all taps
    int plg[2], hG[2], wG[2];
    #pragma unroll
    for (int g = 0; g < 2; ++g) {
        plg[g] = g * 32 + wv * 8 + psub;
        const int pG = pix0 + plg[g];
        hG[g] = pG >> 7;
        wG[g] = pG & 127;
    }

    f32x4 acc[4];
    #pragma unroll
    for (int i = 0; i < 4; ++i) acc[i] = (f32x4){0.f, 0.f, 0.f, 0.f};

    uint4   GB[2][8];        // [tap parity][corner*2 + g]
    __half2 WB[2][2][4];     // [tap parity][g][corner]
    f16x8   AF[2][2];        // [tap parity][k-half]

    auto prep_issue = [&](int k) {
        const int par = k & 1;
        #pragma unroll
        for (int g = 0; g < 2; ++g) {
            const int pl = plg[g];
            const float dy = offl[(2 * k    ) * 64 + pl];   // broadcast reads
            const float dx = offl[(2 * k + 1) * 64 + pl];
            const float mk = offl[(18 + k   ) * 64 + pl];
            const float py  = (float)(hG[g] + k / 3 - 1) + dy;
            const float pxf = (float)(wG[g] + k % 3 - 1) + dx;
            const float y0f = floorf(py), x0f = floorf(pxf);
            const float fy = py - y0f,  fx = pxf - x0f;
            const int y0 = (int)y0f, x0 = (int)x0f;
            const int y1 = y0 + 1,   x1 = x0 + 1;
            const bool vy0 = (y0 >= 0) & (y0 < Hn);
            const bool vy1 = (y1 >= 0) & (y1 < Hn);
            const bool vx0 = (x0 >= 0) & (x0 < Wn);
            const bool vx1 = (x1 >= 0) & (x1 < Wn);
            const float w00 = (1.f - fy) * (1.f - fx) * (float)(vy0 & vx0) * mk;
            const float w01 = (1.f - fy) * fx         * (float)(vy0 & vx1) * mk;
            const float w10 = fy * (1.f - fx)         * (float)(vy1 & vx0) * mk;
            const float w11 = fy * fx                 * (float)(vy1 & vx1) * mk;
            WB[par][g][0] = __float2half2_rn(w00);
            WB[par][g][1] = __float2half2_rn(w01);
            WB[par][g][2] = __float2half2_rn(w10);
            WB[par][g][3] = __float2half2_rn(w11);
            const int y0c = min(max(y0, 0), Hn - 1);
            const int y1c = min(max(y1, 0), Hn - 1);
            const int x0c = min(max(x0, 0), Wn - 1);
            const int x1c = min(max(x1, 0), Wn - 1);
            const int i00 = y0c * Wn + x0c, i01 = y0c * Wn + x1c;
            const int i10 = y1c * Wn + x0c, i11 = y1c * Wn + x1c;
            GB[par][0 + g] = xb[(size_t)i00 * 16 + chunk];
            GB[par][2 + g] = xb[(size_t)i01 * 16 + chunk];
            GB[par][4 + g] = xb[(size_t)i10 * 16 + chunk];
            GB[par][6 + g] = xb[(size_t)i11 * 16 + chunk];
        }
    };

    auto blend_store = [&](int k) {
        const int par = k & 1;
        #pragma unroll
        for (int g = 0; g < 2; ++g) {
            const int pl = plg[g];
            const uint4 g00 = GB[par][0 + g], g01 = GB[par][2 + g];
            const uint4 g10 = GB[par][4 + g], g11 = GB[par][6 + g];
            const unsigned u00[4] = {g00.x, g00.y, g00.z, g00.w};
            const unsigned u01[4] = {g01.x, g01.y, g01.z, g01.w};
            const unsigned u10[4] = {g10.x, g10.y, g10.z, g10.w};
            const unsigned u11[4] = {g11.x, g11.y, g11.z, g11.w};
            unsigned pk[4];
            #pragma unroll
            for (int d = 0; d < 4; ++d) {
                __half2 s = __hmul2(u2h2(u00[d]), WB[par][g][0]);
                s = __hfma2(u2h2(u01[d]), WB[par][g][1], s);
                s = __hfma2(u2h2(u10[d]), WB[par][g][2], s);
                s = __hfma2(u2h2(u11[d]), WB[par][g][3], s);
                pk[d] = h22u(s);
            }
            smp4[par * 512 + pl * 8 + (chunk ^ (pl & 7))] =
                make_uint4(pk[0], pk[1], pk[2], pk[3]);
        }
    };

    auto load_af = [&](int k) {
        const uint4* wpk = wpd + (size_t)((wv * 9 + k) * 2) * 64 + lane;
        AF[k & 1][0] = __builtin_bit_cast(f16x8, wpk[0]);
        AF[k & 1][1] = __builtin_bit_cast(f16x8, wpk[64]);
    };

    // preamble: fill the 2-deep pipe
    prep_issue(0);
    prep_issue(1);
    load_af(0);
    blend_store(0);          // counted vmcnt: waits only tap-0 gathers
    __syncthreads();

    #pragma unroll
    for (int t = 0; t < Kn; ++t) {
        if (t + 1 < Kn) load_af(t + 1);       // A-frags for next tap
        if (t + 2 < Kn) prep_issue(t + 2);    // gathers fly for 2 taps

        const int buf = t & 1;
        #pragma unroll
        for (int nt = 0; nt < 4; ++nt) {
            const int pm = nt * 16 + lrow;
            const f16x8 b0 = __builtin_bit_cast(f16x8,
                smp4[buf * 512 + pm * 8 + ( quad      ^ (pm & 7))]);
            const f16x8 b1 = __builtin_bit_cast(f16x8,
                smp4[buf * 512 + pm * 8 + ((quad + 4) ^ (pm & 7))]);
            acc[nt] = __builtin_amdgcn_mfma_f32_16x16x32_f16(AF[buf][0], b0, acc[nt], 0, 0, 0);
            acc[nt] = __builtin_amdgcn_mfma_f32_16x16x32_f16(AF[buf][1], b1, acc[nt], 0, 0, 0);
        }

        if (t + 1 < Kn) {
            blend_store(t + 1);   // waits tap t+1 gathers; t+2 stay in flight
            __syncthreads();
        }
    }

    const int obase = (wv << 4) + (quad << 2);
    #pragma unroll
    for (int nt = 0; nt < 4; ++nt) {
        const int pp = pix0 + nt * 16 + lrow;
        #pragma unroll
        for (int r = 0; r < 4; ++r)
            out[(size_t)(bb * CO_ + obase + r) * HW + pp] = acc[nt][r];
    }
}

extern "C" void kernel_launch(void* const* d_in, const int* in_sizes, int n_in,
                              void* d_out, int out_size, void* d_ws, size_t ws_size,
                              hipStream_t stream) {
    const float* mem   = (const float*)d_in[0];
    const float* que   = (const float*)d_in[1];
    const float* w_off = (const float*)d_in[2];
    const float* b_off = (const float*)d_in[3];
    const float* w_def = (const float*)d_in[4];
    float* out = (float*)d_out;

    char* ws = (char*)d_ws;
    unsigned short* wpd = (unsigned short*)ws;             //  73,728 B
    unsigned short* wpo = (unsigned short*)(ws + 73728);   //  73,728 B
    uint4*          xT4 = (uint4*)(ws + 147456);           //  33,554,432 B

    transpose_kernel<<<2048, 256, 0, stream>>>(mem, que, xT4);
    wprep_all_kernel<<<288, 256, 0, stream>>>(w_def, w_off, wpd, wpo);
    fused_deform_kernel<<<2048, 256, 0, stream>>>(
        xT4, (const uint4*)wpo, (const uint4*)wpd, b_off, out);
}